// Round 4
// baseline (283.457 us; speedup 1.0000x reference)
//
#include <hip/hip_runtime.h>
#include <hip/hip_bf16.h>
#include <math.h>

// ---------- types ----------
typedef __bf16 bf16x8 __attribute__((ext_vector_type(8)));
typedef float  floatx4 __attribute__((ext_vector_type(4)));

#define MFMA(a, b, c) __builtin_amdgcn_mfma_f32_16x16x32_bf16((a), (b), (c), 0, 0, 0)

__device__ __forceinline__ unsigned short f2bf(float f) {
  union { float f; unsigned u; } v; v.f = f;
  unsigned r = v.u + 0x7FFFu + ((v.u >> 16) & 1u);
  return (unsigned short)(r >> 16);
}
__device__ __forceinline__ float bf2f(unsigned short u) {
  union { unsigned u; float f; } v; v.u = ((unsigned)u) << 16;
  return v.f;
}
// pack two fp32 -> two bf16 (RNE) as one uint
__device__ __forceinline__ unsigned pk2bf(float a, float b) {
  __hip_bfloat162 h = __float22bfloat162_rn(make_float2(a, b));
  union { __hip_bfloat162 h; unsigned u; } v; v.h = h;
  return v.u;
}

// B=4, C=256, N=4096, Ci=32, SPLITS=4
// ---------- K_wconv ----------
__global__ __launch_bounds__(256) void k_wconv(const float* __restrict__ Wq,
                                               const float* __restrict__ Wk,
                                               const float* __restrict__ Wv,
                                               unsigned short* __restrict__ Wall) {
  int i = blockIdx.x * 256 + threadIdx.x;
  int o = i >> 8, c = i & 255;
  float v = (o < 32) ? Wq[o * 256 + c]
          : (o < 64) ? Wk[(o - 32) * 256 + c]
                     : Wv[(o - 64) * 256 + c];
  Wall[i] = f2bf(v);
}

// ---------- K_xpose: x[b][c][n] fp32 -> xT[b][n][c] bf16 ----------
__global__ __launch_bounds__(256) void k_xpose(const float* __restrict__ x,
                                               unsigned short* __restrict__ xT) {
  int bid = blockIdx.x;
  int b = bid >> 8, rem = bid & 255;
  int nb = rem >> 2, cb = rem & 3;
  int n0 = nb * 64, c0 = cb * 64;
  int tid = threadIdx.x;
  __shared__ alignas(16) unsigned short T[64][72];
#pragma unroll
  for (int i = 0; i < 4; ++i) {
    int idx = tid + 256 * i;
    int r = idx >> 4, g = idx & 15;
    float4 d = *(const float4*)(x + ((size_t)b * 256 + c0 + r) * 4096 + n0 + g * 4);
    T[g * 4 + 0][r] = f2bf(d.x);
    T[g * 4 + 1][r] = f2bf(d.y);
    T[g * 4 + 2][r] = f2bf(d.z);
    T[g * 4 + 3][r] = f2bf(d.w);
  }
  __syncthreads();
#pragma unroll
  for (int i = 0; i < 2; ++i) {
    int idx = tid + 256 * i;
    int j = idx >> 3, g = idx & 7;
    *(uint4*)(xT + ((size_t)b * 4096 + n0 + j) * 256 + c0 + g * 8) =
        *(const uint4*)&T[j][g * 8];
  }
}

// ---------- K_proj: 4096 blocks x 1 wave; 16 rows x 5 out-tiles ----------
__global__ __launch_bounds__(64, 4) void k_proj(const unsigned short* __restrict__ xT,
                                                const unsigned short* __restrict__ Wall,
                                                const float* __restrict__ bq,
                                                const float* __restrict__ bk,
                                                const float* __restrict__ bv,
                                                unsigned short* __restrict__ qkT,
                                                unsigned short* __restrict__ vbf) {
  int b = blockIdx.x >> 10;
  int m0 = ((blockIdx.x >> 2) & 255) * 16;
  int h = blockIdx.x & 3;                   // quarter of the 20 output tiles
  int lane = threadIdx.x & 63;
  int l15 = lane & 15, quad = lane >> 4;

  floatx4 acc[5];
#pragma unroll
  for (int tt = 0; tt < 5; ++tt) acc[tt] = floatx4{0.f, 0.f, 0.f, 0.f};

  const unsigned short* arow = xT + ((size_t)b * 4096 + m0 + l15) * 256;
#pragma unroll
  for (int ks = 0; ks < 8; ++ks) {
    bf16x8 a = *(const bf16x8*)(arow + ks * 32 + quad * 8);
#pragma unroll
    for (int tt = 0; tt < 5; ++tt) {
      int gt = (tt == 0) ? h : (4 + h * 4 + (tt - 1));
      bf16x8 w = *(const bf16x8*)(Wall + (size_t)(gt * 16 + l15) * 256 + ks * 32 + quad * 8);
      acc[tt] = MFMA(a, w, acc[tt]);
    }
  }
  // qk tile (outputs h*16 .. h*16+15): direct transposed store
  {
    int o = h * 16 + l15;
    float bias = (o < 32) ? bq[o] : bk[o - 32];
#pragma unroll
    for (int r = 0; r < 4; ++r) {
      int m = m0 + quad * 4 + r;
      qkT[((size_t)b * 4096 + m) * 64 + o] = f2bf(acc[0][r] + bias);
    }
  }
  // v tiles (channels h*64 .. h*64+63): LDS transpose then coalesced stores
  __shared__ alignas(16) unsigned short Os[64][24];
#pragma unroll
  for (int tt = 1; tt < 5; ++tt) {
    int lr = (tt - 1) * 16 + l15;
    float bias = bv[h * 64 + lr];
#pragma unroll
    for (int r = 0; r < 4; ++r)
      Os[lr][quad * 4 + r] = f2bf(acc[tt][r] + bias);
  }
  __syncthreads();
#pragma unroll
  for (int i = 0; i < 2; ++i) {
    int idx = lane + 64 * i;                // 128 granules: r(64) x g(2 x 16B)
    int r = idx >> 1, g = idx & 1;
    *(uint4*)(vbf + ((size_t)b * 256 + h * 64 + r) * 4096 + m0 + g * 8) =
        *(const uint4*)&Os[r][g * 8];
  }
}

// ---------- K_attn: split-K flash attention, no-max softmax ----------
// grid = B*SPLITS*64q*2ch = 2048 blocks of 128 threads (2 waves)
// block: 64 queries x 128 channels; 16 key tiles of 64
__global__ __launch_bounds__(128, 4) void k_attn(const unsigned short* __restrict__ qkT,
                                                 const unsigned short* __restrict__ vbf,
                                                 unsigned short* __restrict__ Obf,
                                                 float* __restrict__ lsum) {
  const int b = blockIdx.x >> 9;
  const int s = (blockIdx.x >> 7) & 3;
  const int chalf = (blockIdx.x >> 6) & 1;
  const int q0 = (blockIdx.x & 63) * 64;
  const int tid = threadIdx.x;
  const int w = tid >> 6, lane = tid & 63;
  const int l15 = lane & 15, quad = lane >> 4;

  // P in A-fragment-chunk layout: [buf][qtile][keychunk(8keys)][query(16)][8]
  __shared__ alignas(16) unsigned short Pl[2][4][8][16][8];   // 16 KB

  const unsigned short* qbase = qkT + (size_t)b * 4096 * 64;
  // Q fragments for this wave's two 16-query groups (qt = 2w, 2w+1)
  bf16x8 aq0 = *(const bf16x8*)(qbase + (size_t)(q0 + (2 * w + 0) * 16 + l15) * 64 + quad * 8);
  bf16x8 aq1 = *(const bf16x8*)(qbase + (size_t)(q0 + (2 * w + 1) * 16 + l15) * 64 + quad * 8);

  floatx4 O[4][4];   // [qt = all 64 queries][nt = this wave's 64 channels]
#pragma unroll
  for (int qt = 0; qt < 4; ++qt)
#pragma unroll
    for (int nt = 0; nt < 4; ++nt) O[qt][nt] = floatx4{0.f, 0.f, 0.f, 0.f};

  float l0 = 0.f, l1 = 0.f;
  const floatx4 zero4 = {0.f, 0.f, 0.f, 0.f};

  // V base: this wave's 64 channels
  const unsigned short* vrow = vbf + ((size_t)b * 256 + chalf * 128 + w * 64) * 4096;
  // K base (channels 32..63 of qkT rows)
  const unsigned short* krow = qbase + 32;

  for (int it = 0; it < 16; ++it) {
    const int m0 = (s * 16 + it) * 64;
    const int pb = it & 1;

    // K fragments straight from L2 (same for both waves)
    bf16x8 kb[4];
#pragma unroll
    for (int t = 0; t < 4; ++t)
      kb[t] = *(const bf16x8*)(krow + (size_t)(m0 + t * 16 + l15) * 64 + quad * 8);
    // V fragments straight from L2 (consumed after the barrier)
    bf16x8 vb[4][2];
#pragma unroll
    for (int nt = 0; nt < 4; ++nt)
#pragma unroll
      for (int kk = 0; kk < 2; ++kk)
        vb[nt][kk] = *(const bf16x8*)(vrow + (size_t)(nt * 16 + l15) * 4096 + m0 + kk * 32 + quad * 8);

    // ---- S^T: rows = keys (4 consecutive per lane), cols = queries ----
    const int qk_hi = quad >> 1, qk_lo = (quad & 1) * 4;
#pragma unroll
    for (int g = 0; g < 2; ++g) {
#pragma unroll
      for (int t = 0; t < 4; ++t) {
        floatx4 st = MFMA(kb[t], g ? aq1 : aq0, zero4);
        float p0 = __expf(st[0]);
        float p1 = __expf(st[1]);
        float p2 = __expf(st[2]);
        float p3 = __expf(st[3]);
        float sm = (p0 + p1) + (p2 + p3);
        if (g) l1 += sm; else l0 += sm;
        uint2 pk = make_uint2(pk2bf(p0, p1), pk2bf(p2, p3));
        *(uint2*)&Pl[pb][2 * w + g][2 * t + qk_hi][l15][qk_lo] = pk;
      }
    }
    __syncthreads();   // P ready

    // ---- PV: all 64 queries x this wave's 64 channels ----
#pragma unroll
    for (int qt = 0; qt < 4; ++qt) {
      bf16x8 pa0 = *(const bf16x8*)&Pl[pb][qt][quad][l15][0];
      bf16x8 pa1 = *(const bf16x8*)&Pl[pb][qt][quad + 4][l15][0];
#pragma unroll
      for (int nt = 0; nt < 4; ++nt) {
        O[qt][nt] = MFMA(pa0, vb[nt][0], O[qt][nt]);
        O[qt][nt] = MFMA(pa1, vb[nt][1], O[qt][nt]);
      }
    }
  }

  // ---- epilogue ----
  // l: reduce over quads (lanes sharing l15 hold the same query)
  l0 += __shfl_xor(l0, 16); l0 += __shfl_xor(l0, 32);
  l1 += __shfl_xor(l1, 16); l1 += __shfl_xor(l1, 32);
  if (chalf == 0 && quad == 0) {
    size_t base = ((size_t)s * 4 + b) * 4096 + q0;
    lsum[base + (2 * w + 0) * 16 + l15] = l0;
    lsum[base + (2 * w + 1) * 16 + l15] = l1;
  }

  // O: direct packed stores (4 consecutive queries per lane per frag)
#pragma unroll
  for (int nt = 0; nt < 4; ++nt) {
    size_t crow = (((size_t)s * 4 + b) * 256 + chalf * 128 + w * 64 + nt * 16 + l15) * 4096;
#pragma unroll
    for (int qt = 0; qt < 4; ++qt) {
      uint2 ok = make_uint2(pk2bf(O[qt][nt][0], O[qt][nt][1]),
                            pk2bf(O[qt][nt][2], O[qt][nt][3]));
      *(uint2*)(Obf + crow + q0 + qt * 16 + quad * 4) = ok;
    }
  }
}

// ---------- K_merge: out = x + gamma * (sum_s O_s) / (sum_s l_s) ----------
__global__ __launch_bounds__(256) void k_merge(const unsigned short* __restrict__ Obf,
                                               const float* __restrict__ lsum,
                                               const float* __restrict__ x,
                                               const float* __restrict__ gma,
                                               float* __restrict__ out) {
  int t = blockIdx.x * 256 + threadIdx.x;
  int n4 = t & 1023;
  int c = (t >> 10) & 255;
  int b = t >> 18;
  int n = n4 << 2;
  size_t xa = (((size_t)b * 256 + c) << 12) + n;
  float4 xv = *(const float4*)(x + xa);
  float L0 = 0.f, L1 = 0.f, L2 = 0.f, L3 = 0.f;
  float o0 = 0.f, o1 = 0.f, o2 = 0.f, o3 = 0.f;
#pragma unroll
  for (int s = 0; s < 4; ++s) {
    float4 ls = *(const float4*)(lsum + (((size_t)s * 4 + b) << 12) + n);
    L0 += ls.x; L1 += ls.y; L2 += ls.z; L3 += ls.w;
    ushort4 ov = *(const ushort4*)(Obf + ((((size_t)s * 4 + b) * 256 + c) << 12) + n);
    o0 += bf2f(ov.x); o1 += bf2f(ov.y); o2 += bf2f(ov.z); o3 += bf2f(ov.w);
  }
  float g = gma[0];
  float4 r;
  r.x = xv.x + g * o0 / L0;
  r.y = xv.y + g * o1 / L1;
  r.z = xv.z + g * o2 / L2;
  r.w = xv.w + g * o3 / L3;
  *(float4*)(out + xa) = r;
}

// ---------- launch ----------
extern "C" void kernel_launch(void* const* d_in, const int* in_sizes, int n_in,
                              void* d_out, int out_size, void* d_ws, size_t ws_size,
                              hipStream_t stream) {
  const float* x   = (const float*)d_in[0];
  const float* Wq  = (const float*)d_in[1];
  const float* bq  = (const float*)d_in[2];
  const float* Wk  = (const float*)d_in[3];
  const float* bk  = (const float*)d_in[4];
  const float* Wv  = (const float*)d_in[5];
  const float* bv  = (const float*)d_in[6];
  const float* gma = (const float*)d_in[7];
  float* out = (float*)d_out;

  // layout: [qkT][vbf][Wall][ xT (dead after k_proj) -> Obf ][lsum]
  unsigned short* qkT  = (unsigned short*)d_ws;              // [4][4096][64]
  unsigned short* vbf  = qkT + (size_t)4 * 4096 * 64;        // [4][256][4096]
  unsigned short* Wall = vbf + (size_t)4 * 256 * 4096;       // [320][256]
  unsigned short* xT   = Wall + (size_t)320 * 256;           // [4][4096][256]
  unsigned short* Obf  = xT;                                 // [4s][4b][256][4096]
  float* lsum = (float*)(Obf + (size_t)4 * 4 * 256 * 4096);  // [4s][4b][4096]

  k_wconv<<<320, 256, 0, stream>>>(Wq, Wk, Wv, Wall);
  k_xpose<<<1024, 256, 0, stream>>>(x, xT);
  k_proj<<<4096, 64, 0, stream>>>(xT, Wall, bq, bk, bv, qkT, vbf);
  k_attn<<<2048, 128, 0, stream>>>(qkT, vbf, Obf, lsum);
  k_merge<<<4096, 256, 0, stream>>>(Obf, lsum, x, gma, out);
}

// Round 5
// 195.133 us; speedup vs baseline: 1.4526x; 1.4526x over previous
//
#include <hip/hip_runtime.h>
#include <hip/hip_bf16.h>
#include <math.h>

// ---------- types ----------
typedef __bf16 bf16x8 __attribute__((ext_vector_type(8)));
typedef float  floatx4 __attribute__((ext_vector_type(4)));

#define MFMA(a, b, c) __builtin_amdgcn_mfma_f32_16x16x32_bf16((a), (b), (c), 0, 0, 0)

__device__ __forceinline__ unsigned short f2bf(float f) {
  union { float f; unsigned u; } v; v.f = f;
  unsigned r = v.u + 0x7FFFu + ((v.u >> 16) & 1u);
  return (unsigned short)(r >> 16);
}
__device__ __forceinline__ float bf2f(unsigned short u) {
  union { unsigned u; float f; } v; v.u = ((unsigned)u) << 16;
  return v.f;
}
// pack two fp32 -> two bf16 (RNE) as one uint
__device__ __forceinline__ unsigned pk2bf(float a, float b) {
  __hip_bfloat162 h = __float22bfloat162_rn(make_float2(a, b));
  union { __hip_bfloat162 h; unsigned u; } v; v.h = h;
  return v.u;
}

// B=4, C=256, N=4096, Ci=32, SPLITS=4
// ---------- K_wconv: Wall[320][256] bf16 = [Wq;Wk;Wv] ----------
__global__ __launch_bounds__(256) void k_wconv(const float* __restrict__ Wq,
                                               const float* __restrict__ Wk,
                                               const float* __restrict__ Wv,
                                               unsigned short* __restrict__ Wall) {
  int i = blockIdx.x * 256 + threadIdx.x;
  int o = i >> 8, c = i & 255;
  float v = (o < 32) ? Wq[o * 256 + c]
          : (o < 64) ? Wk[(o - 32) * 256 + c]
                     : Wv[(o - 64) * 256 + c];
  Wall[i] = f2bf(v);
}

// ---------- K_proj (fused transpose): 1024 blocks x 1 wave ----------
// block = (b, m-tile of 16 rows); stages x[b][:][m0:m0+16] -> LDS bf16 [16][264],
// then 20 output tiles (4 qk + 16 v) via MFMA.
__global__ __launch_bounds__(64, 3) void k_proj(const float* __restrict__ x,
                                                const unsigned short* __restrict__ Wall,
                                                const float* __restrict__ bq,
                                                const float* __restrict__ bk,
                                                const float* __restrict__ bv,
                                                unsigned short* __restrict__ qkT,
                                                unsigned short* __restrict__ vbf) {
  int b = blockIdx.x >> 8;
  int m0 = (blockIdx.x & 255) * 16;
  int lane = threadIdx.x;
  int l15 = lane & 15, quad = lane >> 4;

  __shared__ alignas(16) union {
    unsigned short T[16][264];     // [n][c] A-tile, pad 264 (8.4 KB)
    unsigned short Os[256][24];    // [c][m] v epilogue staging (12.3 KB)
  } sm;

  // stage + transpose: x[b][c][m0+n] fp32 -> T[n][c] bf16 (c-pairs packed)
  const float* xb = x + (size_t)b * 256 * 4096 + m0;
#pragma unroll
  for (int i = 0; i < 8; ++i) {
    int idx = i * 64 + lane;            // 512 granules: cp(128) x nq(4)
    int cp = idx >> 2, nq = idx & 3;
    float4 fa = *(const float4*)(xb + (size_t)(2 * cp) * 4096 + nq * 4);
    float4 fb = *(const float4*)(xb + (size_t)(2 * cp + 1) * 4096 + nq * 4);
    *(unsigned*)&sm.T[nq * 4 + 0][2 * cp] = pk2bf(fa.x, fb.x);
    *(unsigned*)&sm.T[nq * 4 + 1][2 * cp] = pk2bf(fa.y, fb.y);
    *(unsigned*)&sm.T[nq * 4 + 2][2 * cp] = pk2bf(fa.z, fb.z);
    *(unsigned*)&sm.T[nq * 4 + 3][2 * cp] = pk2bf(fa.w, fb.w);
  }
  __syncthreads();

  floatx4 acc[20];
#pragma unroll
  for (int tt = 0; tt < 20; ++tt) acc[tt] = floatx4{0.f, 0.f, 0.f, 0.f};

#pragma unroll
  for (int ks = 0; ks < 8; ++ks) {
    bf16x8 a = *(const bf16x8*)&sm.T[l15][ks * 32 + quad * 8];
#pragma unroll
    for (int tt = 0; tt < 20; ++tt) {
      bf16x8 w = *(const bf16x8*)(Wall + (size_t)(tt * 16 + l15) * 256 + ks * 32 + quad * 8);
      acc[tt] = MFMA(a, w, acc[tt]);
    }
  }
  // qk tiles 0..3: direct transposed store
#pragma unroll
  for (int tt = 0; tt < 4; ++tt) {
    int o = tt * 16 + l15;
    float bias = (o < 32) ? bq[o] : bk[o - 32];
#pragma unroll
    for (int r = 0; r < 4; ++r) {
      int m = m0 + quad * 4 + r;
      qkT[((size_t)b * 4096 + m) * 64 + o] = f2bf(acc[tt][r] + bias);
    }
  }
  // v tiles 4..19: LDS transpose then coalesced stores
  __syncthreads();   // done reading T before Os overwrites (union)
#pragma unroll
  for (int tt = 4; tt < 20; ++tt) {
    int c = (tt - 4) * 16 + l15;
    float bias = bv[c];
#pragma unroll
    for (int r = 0; r < 4; ++r)
      sm.Os[c][quad * 4 + r] = f2bf(acc[tt][r] + bias);
  }
  __syncthreads();
#pragma unroll
  for (int i = 0; i < 8; ++i) {
    int idx = lane + 64 * i;            // 512 granules: r(256 c) x g(2 x 16B)
    int r = idx >> 1, g = idx & 1;
    *(uint4*)(vbf + ((size_t)b * 256 + r) * 4096 + m0 + g * 8) = *(const uint4*)&sm.Os[r][g * 8];
  }
}

// ---------- K_attn: split-K flash attention, no-max softmax ----------
// grid = B*SPLITS*64; block = 4 waves, 64 queries x 256 ch; 16 key tiles of 64
__global__ __launch_bounds__(256, 4) void k_attn(const unsigned short* __restrict__ qkT,
                                                 const unsigned short* __restrict__ vbf,
                                                 unsigned short* __restrict__ Obf,
                                                 float* __restrict__ lsum) {
  const int b = blockIdx.x >> 8;
  const int s = (blockIdx.x >> 6) & 3;
  const int q0 = (blockIdx.x & 63) * 64;
  const int tid = threadIdx.x;
  const int wave = tid >> 6, lane = tid & 63;
  const int l15 = lane & 15, quad = lane >> 4;

  __shared__ alignas(16) unsigned short Kl[2][64][40];        // K dbuf, 10 KB
  __shared__ alignas(16) unsigned short Pl[2][4][8][16][8];   // P dbuf (A-frag chunks), 16 KB

  const unsigned short* qbase = qkT + (size_t)b * 4096 * 64;
  // Q fragment (B-operand): row = this wave's 16 queries, cols = ch 0..31
  bf16x8 aq = *(const bf16x8*)(qbase + (size_t)(q0 + wave * 16 + l15) * 64 + quad * 8);

  floatx4 O[4][4];   // [qt = all 64 queries][nt = this wave's 64 channels]
#pragma unroll
  for (int qt = 0; qt < 4; ++qt)
#pragma unroll
    for (int nt = 0; nt < 4; ++nt) O[qt][nt] = floatx4{0.f, 0.f, 0.f, 0.f};

  float l_part = 0.f;
  const floatx4 zero4 = {0.f, 0.f, 0.f, 0.f};

  const unsigned short* vrow = vbf + ((size_t)b * 256 + wave * 64) * 4096;

  // prologue: stage K tile 0 -> Kl[0]
  {
    int r = tid >> 2, g = tid & 3;
    uint4 d = *(const uint4*)(qbase + (size_t)(s * 1024 + r) * 64 + 32 + g * 8);
    *(uint4*)&Kl[0][r][g * 8] = d;
  }
  __syncthreads();

  const int kc_hi = quad >> 1, kc_lo = (quad & 1) * 4;

  for (int it = 0; it < 16; ++it) {
    const int m0 = (s * 16 + it) * 64;
    const int buf = it & 1;

    // V fragments straight from global (consumed after the barrier)
    bf16x8 vb[4][2];
#pragma unroll
    for (int nt = 0; nt < 4; ++nt)
#pragma unroll
      for (int kk = 0; kk < 2; ++kk)
        vb[nt][kk] = *(const bf16x8*)(vrow + (size_t)(nt * 16 + l15) * 4096 + m0 + kk * 32 + quad * 8);

    // ---- S^T: D[key][query]; keys quad*4+r in chunk t, query = l15 ----
#pragma unroll
    for (int t = 0; t < 4; ++t) {
      bf16x8 kb = *(const bf16x8*)&Kl[buf][t * 16 + l15][quad * 8];
      floatx4 st = MFMA(kb, aq, zero4);
      float p0 = __expf(st[0]);
      float p1 = __expf(st[1]);
      float p2 = __expf(st[2]);
      float p3 = __expf(st[3]);
      l_part += (p0 + p1) + (p2 + p3);
      uint2 pk = make_uint2(pk2bf(p0, p1), pk2bf(p2, p3));
      *(uint2*)&Pl[buf][wave][2 * t + kc_hi][l15][kc_lo] = pk;
    }

    // stage next K tile into the other buffer
    if (it < 15) {
      int r = tid >> 2, g = tid & 3;
      uint4 d = *(const uint4*)(qbase + (size_t)(m0 + 64 + r) * 64 + 32 + g * 8);
      *(uint4*)&Kl[buf ^ 1][r][g * 8] = d;
    }
    __syncthreads();   // P ready; K(it+1) staged

    // ---- PV: all 64 queries x this wave's 64 channels ----
#pragma unroll
    for (int qt = 0; qt < 4; ++qt) {
      bf16x8 pa0 = *(const bf16x8*)&Pl[buf][qt][quad][l15][0];
      bf16x8 pa1 = *(const bf16x8*)&Pl[buf][qt][quad + 4][l15][0];
#pragma unroll
      for (int nt = 0; nt < 4; ++nt) {
        O[qt][nt] = MFMA(pa0, vb[nt][0], O[qt][nt]);
        O[qt][nt] = MFMA(pa1, vb[nt][1], O[qt][nt]);
      }
    }
  }

  // ---- epilogue ----
  l_part += __shfl_xor(l_part, 16);
  l_part += __shfl_xor(l_part, 32);
  if (quad == 0)
    lsum[((size_t)s * 4 + b) * 4096 + q0 + wave * 16 + l15] = l_part;

  // O: packed stores (4 consecutive queries per lane per frag)
#pragma unroll
  for (int nt = 0; nt < 4; ++nt) {
    size_t crow = (((size_t)s * 4 + b) * 256 + wave * 64 + nt * 16 + l15) * 4096;
#pragma unroll
    for (int qt = 0; qt < 4; ++qt) {
      uint2 ok = make_uint2(pk2bf(O[qt][nt][0], O[qt][nt][1]),
                            pk2bf(O[qt][nt][2], O[qt][nt][3]));
      *(uint2*)(Obf + crow + q0 + qt * 16 + quad * 4) = ok;
    }
  }
}

// ---------- K_merge: out = x + gamma * (sum_s O_s) / (sum_s l_s) ----------
__global__ __launch_bounds__(256) void k_merge(const unsigned short* __restrict__ Obf,
                                               const float* __restrict__ lsum,
                                               const float* __restrict__ x,
                                               const float* __restrict__ gma,
                                               float* __restrict__ out) {
  int t = blockIdx.x * 256 + threadIdx.x;
  int n4 = t & 1023;
  int c = (t >> 10) & 255;
  int b = t >> 18;
  int n = n4 << 2;
  size_t xa = (((size_t)b * 256 + c) << 12) + n;
  float4 xv = *(const float4*)(x + xa);
  float L0 = 0.f, L1 = 0.f, L2 = 0.f, L3 = 0.f;
  float o0 = 0.f, o1 = 0.f, o2 = 0.f, o3 = 0.f;
#pragma unroll
  for (int s = 0; s < 4; ++s) {
    float4 ls = *(const float4*)(lsum + (((size_t)s * 4 + b) << 12) + n);
    L0 += ls.x; L1 += ls.y; L2 += ls.z; L3 += ls.w;
    ushort4 ov = *(const ushort4*)(Obf + ((((size_t)s * 4 + b) * 256 + c) << 12) + n);
    o0 += bf2f(ov.x); o1 += bf2f(ov.y); o2 += bf2f(ov.z); o3 += bf2f(ov.w);
  }
  float g = gma[0];
  float4 r;
  r.x = xv.x + g * o0 / L0;
  r.y = xv.y + g * o1 / L1;
  r.z = xv.z + g * o2 / L2;
  r.w = xv.w + g * o3 / L3;
  *(float4*)(out + xa) = r;
}

// ---------- launch ----------
extern "C" void kernel_launch(void* const* d_in, const int* in_sizes, int n_in,
                              void* d_out, int out_size, void* d_ws, size_t ws_size,
                              hipStream_t stream) {
  const float* x   = (const float*)d_in[0];
  const float* Wq  = (const float*)d_in[1];
  const float* bq  = (const float*)d_in[2];
  const float* Wk  = (const float*)d_in[3];
  const float* bk  = (const float*)d_in[4];
  const float* Wv  = (const float*)d_in[5];
  const float* bv  = (const float*)d_in[6];
  const float* gma = (const float*)d_in[7];
  float* out = (float*)d_out;

  unsigned short* qkT  = (unsigned short*)d_ws;              // [4][4096][64]
  unsigned short* vbf  = qkT + (size_t)4 * 4096 * 64;        // [4][256][4096]
  unsigned short* Wall = vbf + (size_t)4 * 256 * 4096;       // [320][256]
  unsigned short* Obf  = Wall + (size_t)320 * 256;           // [4s][4b][256][4096]
  float* lsum = (float*)(Obf + (size_t)4 * 4 * 256 * 4096);  // [4s][4b][4096]

  k_wconv<<<320, 256, 0, stream>>>(Wq, Wk, Wv, Wall);
  k_proj<<<1024, 64, 0, stream>>>(x, Wall, bq, bk, bv, qkT, vbf);
  k_attn<<<1024, 256, 0, stream>>>(qkT, vbf, Obf, lsum);
  k_merge<<<4096, 256, 0, stream>>>(Obf, lsum, x, gma, out);
}